// Round 5
// baseline (285.777 us; speedup 1.0000x reference)
//
#include <hip/hip_runtime.h>
#include <math.h>

// Problem constants (from reference): T=128, B=2048, D=256, ALPHA=0.5, VTH=1.0
#define TT 128
#define BB 2048
#define DDIM 256
#define BD (BB * DDIM)

// Computes c[j] = cumprod_{i=1..j}(1 - 1.5/i) in f64 -> f32, bit-identical to
// np.float64 cumprod + astype(float32) (same IEEE op sequence). Runtime values
// (not constexpr-visible) so the main kernel must s_load them -> SGPR operands
// in v_fma (VOP3 allows 1 SGPR src), killing the per-FMA literal-mov.
__global__ void coeff_init_kernel(float* __restrict__ c) {
    if (blockIdx.x == 0 && threadIdx.x == 0) {
        c[0] = 1.0f;
        double cur = 1.0;
        for (int j = 1; j < TT; ++j) {
            cur *= (1.0 - 1.5 / (double)j);
            c[j] = (float)cur;
        }
    }
}

// One thread per (b,d) sequence, full y-history in ARCH VGPRs.
//
// R1-R4 post-mortem: the register allocator targets max occupancy, caps arch
// VGPRs at ~72, and shuttles y[128] through AGPRs -- VALU can't read AGPRs,
// so every FMA paid a companion copy (19K VALU instrs/wave vs ~9.5K floor).
// waves_per_eu / launch_bounds set FLOORS (never binding -> identical
// binaries). The lever that actually lowers the allocator's occupancy target:
// LDS. 48 KiB ballast -> 3 blocks/CU -> 3 waves/SIMD -> ~170-reg budget ->
// y[] fits in arch VGPRs with zero spills -> 1 VALU instr per FMA.
__global__ __launch_bounds__(256) void gl_if_kernel(const float* __restrict__ x,
                                                    float* __restrict__ sp,
                                                    const float* __restrict__ C) {
    __shared__ float lds_ballast[12288];  // 48 KiB: occupancy governor

    const int g = blockIdx.x * 256 + threadIdx.x;  // (b,d) flat index

    // Keep the LDS genuinely live (write + read feeding an asm sink) so
    // neither the array nor the occupancy cap can be optimized away.
    lds_ballast[threadIdx.x] = x[g];
    float keep = lds_ballast[(threadIdx.x + 7) & 255];
    asm volatile("" ::"v"(keep));

    float y[TT];  // y[i] = reset membrane of step i+1

    // depth-2 prefetch: cover HBM latency at 3 waves/SIMD
    float xa = x[g];            // x for step 1
    float xb = x[g + BD];       // x for step 2

#pragma unroll
    for (int k = 1; k <= TT; ++k) {
        float xc = 0.0f;
        if (k + 2 <= TT) {
            xc = x[g + (size_t)(k + 1) * BD];  // x for step k+2
        }
        // right = sum over slots i < k-1 of c[k-1-i] * y[i], slot-ascending
        // (identical fmaf chain to the passing R1 kernel; C[] values are
        // bit-identical to the constexpr table)
        float acc = 0.0f;
#pragma unroll
        for (int i = 0; i <= k - 2; ++i) {
            acc = fmaf(C[k - 1 - i], y[i], acc);
        }
        const float men0 = xa - acc;
        const float spike = (men0 > 1.0f) ? 1.0f : 0.0f;
        y[k - 1] = men0 - spike;  // VTH = 1.0
        sp[g + (size_t)(k - 1) * BD] = spike;
        xa = xb;
        xb = xc;
    }
}

// Lorentz expmap: per row b, vv = -v0^2 + sum_{d>=1} vd^2; s = sqrt(max(vv,eps));
// out = cosh(s)*z + (sinh(s)/s)*v.  One block per row, one thread per d.
__global__ __launch_bounds__(256) void expmap_kernel(const float* __restrict__ v,
                                                     const float* __restrict__ z,
                                                     float* __restrict__ out) {
    const int b = blockIdx.x;
    const int d = threadIdx.x;
    const size_t idx = (size_t)b * DDIM + d;
    const float vd = v[idx];

    float term = vd * vd;
    if (d == 0) term = -term;

    // reduce across the 256-thread block (4 waves of 64)
    float sum = term;
#pragma unroll
    for (int off = 32; off > 0; off >>= 1) sum += __shfl_down(sum, off, 64);

    __shared__ float ws[4];
    if ((threadIdx.x & 63) == 0) ws[threadIdx.x >> 6] = sum;
    __syncthreads();
    const float vv = ws[0] + ws[1] + ws[2] + ws[3];

    const float s2 = fmaxf(vv, 1e-6f);
    const float s = sqrtf(s2);
    const float ch = coshf(s);
    const float shs = sinhf(s) / s;

    out[idx] = ch * z[idx] + shs * vd;
}

extern "C" void kernel_launch(void* const* d_in, const int* in_sizes, int n_in,
                              void* d_out, int out_size, void* d_ws, size_t ws_size,
                              hipStream_t stream) {
    const float* x_seq = (const float*)d_in[0];
    const float* v_seq = (const float*)d_in[1];
    const float* z_seq = (const float*)d_in[2];

    float* s_out = (float*)d_out;                       // [T,B,D] spikes
    float* z_out = (float*)d_out + (size_t)TT * BD;     // [B,D] expmap
    float* coeffs = (float*)d_ws;                       // 128 floats of scratch

    coeff_init_kernel<<<1, 64, 0, stream>>>(coeffs);
    gl_if_kernel<<<BD / 256, 256, 0, stream>>>(x_seq, s_out, coeffs);
    expmap_kernel<<<BB, DDIM, 0, stream>>>(v_seq, z_seq, z_out);
}

// Round 6
// 135.155 us; speedup vs baseline: 2.1144x; 2.1144x over previous
//
#include <hip/hip_runtime.h>
#include <math.h>

// Problem constants (from reference): T=128, B=2048, D=256, ALPHA=0.5, VTH=1.0
#define TT 128
#define BB 2048
#define DDIM 256
#define BD (BB * DDIM)

// GL coefficients c[j] = prod_{i=1..j} (1 - (1+alpha)/i), computed in f64 then
// cast to f32 — exactly mirrors _gl_coeffs (float64 cumprod -> float32 cast).
struct Coeffs {
    float c[TT + 1];
};
static constexpr Coeffs make_coeffs() {
    Coeffs r{};
    r.c[0] = 1.0f;
    double cur = 1.0;
    for (int j = 1; j <= TT; ++j) {
        cur *= (1.0 - 1.5 / (double)j);  // (1+alpha) = 1.5
        r.c[j] = (float)cur;
    }
    return r;
}
static constexpr Coeffs CO = make_coeffs();

// One thread per (b,d) sequence, full y-history intended for ARCH VGPRs.
//
// R1-R5 post-mortem: 19K VALU instrs/wave is invariant under launch_bounds,
// waves_per_eu, SGPR coeffs, inline asm, and a 48KiB LDS occupancy ballast --
// VGPR_Count pinned at 72 every time. Model: the backend commits y[128] to
// AGPRs independent of the occupancy budget; every FMA then pays one
// v_accvgpr_read (VALU cannot source AGPRs) = 2 ops/FMA. amdgpu_num_vgpr is
// the one knob that SETS the allocation (not a floor hint). 256 regs ->
// 2 waves/SIMD; depth-2 prefetch covers HBM latency at that occupancy.
// Math is the exact R1 fmaf chain -> bit-identical output.
__global__
__attribute__((amdgpu_flat_work_group_size(256, 256), amdgpu_num_vgpr(256)))
void gl_if_kernel(const float* __restrict__ x, float* __restrict__ sp) {
    const int g = blockIdx.x * 256 + threadIdx.x;  // (b,d) flat index
    const float* __restrict__ xp = x + g;
    float* __restrict__ spp = sp + g;
    float y[TT];  // y[i] = reset membrane of step i+1

    // depth-2 prefetch
    float xa = xp[0];
    float xb = xp[BD];
    xp += 2 * (size_t)BD;

#pragma unroll
    for (int k = 1; k <= TT; ++k) {
        float xc = 0.0f;
        if (k + 2 <= TT) {
            xc = *xp;
            xp += BD;
        }
        // right = sum over buffer slots i < k-1 of c[k-1-i] * y[i]
        // (slot-ascending; identical chain to the passing R1 kernel)
        float acc = 0.0f;
#pragma unroll
        for (int i = 0; i <= k - 2; ++i) {
            acc = fmaf(CO.c[k - 1 - i], y[i], acc);
        }
        const float men0 = xa - acc;
        const float spike = (men0 > 1.0f) ? 1.0f : 0.0f;
        y[k - 1] = men0 - spike;  // VTH = 1.0
        *spp = spike;
        spp += BD;
        xa = xb;
        xb = xc;
    }
}

// Lorentz expmap: per row b, vv = -v0^2 + sum_{d>=1} vd^2; s = sqrt(max(vv,eps));
// out = cosh(s)*z + (sinh(s)/s)*v.  One block per row, one thread per d.
__global__ __launch_bounds__(256) void expmap_kernel(const float* __restrict__ v,
                                                     const float* __restrict__ z,
                                                     float* __restrict__ out) {
    const int b = blockIdx.x;
    const int d = threadIdx.x;
    const size_t idx = (size_t)b * DDIM + d;
    const float vd = v[idx];

    float term = vd * vd;
    if (d == 0) term = -term;

    // reduce across the 256-thread block (4 waves of 64)
    float sum = term;
#pragma unroll
    for (int off = 32; off > 0; off >>= 1) sum += __shfl_down(sum, off, 64);

    __shared__ float ws[4];
    if ((threadIdx.x & 63) == 0) ws[threadIdx.x >> 6] = sum;
    __syncthreads();
    const float vv = ws[0] + ws[1] + ws[2] + ws[3];

    const float s2 = fmaxf(vv, 1e-6f);
    const float s = sqrtf(s2);
    const float ch = coshf(s);
    const float shs = sinhf(s) / s;

    out[idx] = ch * z[idx] + shs * vd;
}

extern "C" void kernel_launch(void* const* d_in, const int* in_sizes, int n_in,
                              void* d_out, int out_size, void* d_ws, size_t ws_size,
                              hipStream_t stream) {
    const float* x_seq = (const float*)d_in[0];
    const float* v_seq = (const float*)d_in[1];
    const float* z_seq = (const float*)d_in[2];

    float* s_out = (float*)d_out;                       // [T,B,D] spikes
    float* z_out = (float*)d_out + (size_t)TT * BD;     // [B,D] expmap

    gl_if_kernel<<<BD / 256, 256, 0, stream>>>(x_seq, s_out);
    expmap_kernel<<<BB, DDIM, 0, stream>>>(v_seq, z_seq, z_out);
}